// Round 8
// baseline (242.727 us; speedup 1.0000x reference)
//
#include <hip/hip_runtime.h>
#include <hip/hip_bf16.h>

// Problem constants (reference: B=2, S=2048, D=1024, H=16, DEPTH=64)
constexpr int Bn = 2, Sn = 2048, Dn = 1024, Hn = 16, DEP = 64;
constexpr int NTOKn = Bn * Sn;  // 4096 rows for the token-dim GEMMs

typedef __bf16 bf16x8 __attribute__((ext_vector_type(8)));
typedef float f32x4 __attribute__((ext_vector_type(4)));

__device__ __forceinline__ unsigned short f2bf(float f) {
    union { __hip_bfloat16 h; unsigned short u; } cv;
    cv.h = __float2bfloat16(f);
    return cv.u;
}

// async global->LDS, 16B per lane. LDS dest must be wave-uniform base + lane*16.
__device__ __forceinline__ void gll16(const void* g, void* l) {
    __builtin_amdgcn_global_load_lds(
        (const __attribute__((address_space(1))) unsigned int*)g,
        (__attribute__((address_space(3))) unsigned int*)l, 16, 0, 0);
}

// ---------------- fused prep: x f32->bf16 convert + 4x weight transpose ----------------
__global__ __launch_bounds__(256) void k_prep(const float* __restrict__ x,
                                              const float* __restrict__ w0,
                                              const float* __restrict__ w1,
                                              const float* __restrict__ w2,
                                              const float* __restrict__ w3,
                                              unsigned short* __restrict__ xb,
                                              unsigned short* __restrict__ t0,
                                              unsigned short* __restrict__ t1,
                                              unsigned short* __restrict__ t2,
                                              unsigned short* __restrict__ t3) {
    const int bid = blockIdx.x;
    const int t = threadIdx.x;
    if (bid < 4096) {
        const int idx = (bid * 256 + t) * 4;
        float4 v = *reinterpret_cast<const float4*>(x + idx);
        ushort4 o;
        o.x = f2bf(v.x); o.y = f2bf(v.y); o.z = f2bf(v.z); o.w = f2bf(v.w);
        *reinterpret_cast<ushort4*>(xb + idx) = o;
        return;
    }
    const int b2 = bid - 4096;
    const float* w; unsigned short* tp;
    switch (b2 >> 8) {
        case 0: w = w0; tp = t0; break;
        case 1: w = w1; tp = t1; break;
        case 2: w = w2; tp = t2; break;
        default: w = w3; tp = t3; break;
    }
    __shared__ unsigned short tile[64][65];
    const int k0 = ((b2 & 255) >> 4) * 64, n0 = (b2 & 15) * 64;
    const int c = t & 63, rb = t >> 6;
#pragma unroll
    for (int i = 0; i < 16; ++i) {
        int r = rb + i * 4;
        tile[r][c] = f2bf(w[(size_t)(k0 + r) * Dn + n0 + c]);
    }
    __syncthreads();
#pragma unroll
    for (int i = 0; i < 16; ++i) {
        int n = rb + i * 4;
        tp[(size_t)(n0 + n) * Dn + k0 + c] = tile[c][n];
    }
}

// =================== QKV GEMM, 8-phase-style 256x256 tile ===================
// (counted vmcnt(4), T2 slot-swizzle, T5 setprio)
// Epilogue: Q/K blocks write qkv[z][token][dim]; V blocks (z==2) write the
// TRANSPOSED vT[(b*1024+col)][s] directly as ushort4.
__global__ __launch_bounds__(512, 2) void k_qkv8(const unsigned short* __restrict__ A,
                                                 const unsigned short* __restrict__ Bt,
                                                 const float* __restrict__ bq,
                                                 const float* __restrict__ bk,
                                                 const float* __restrict__ bv,
                                                 unsigned short* __restrict__ qkv,
                                                 unsigned short* __restrict__ vT) {
    extern __shared__ char smem[];  // 131072 bytes
    constexpr int K = 1024, NT = K / 64;  // 16 K-steps

    const int t = threadIdx.x;
    const int w = t >> 6, l = t & 63;
    const int wm = w >> 2, wn = w & 3;
    const int m0 = blockIdx.x * 256;
    const int n0 = blockIdx.y * 256;
    const int z = n0 >> 10;

    const float* bias = (z == 0) ? bq : (z == 1 ? bk : bv);
    float biasv[4];
#pragma unroll
    for (int nf = 0; nf < 4; ++nf)
        biasv[nf] = bias[(n0 + wn * 64 + nf * 16 + (l & 15)) & 1023];

    int aoff[2], boff[2], ldsoff[2];
#pragma unroll
    for (int i = 0; i < 2; ++i) {
        const int idx = i * 512 + t;
        const int row = idx >> 2;
        const int s = ((idx & 3) - row - (row >> 2)) & 3;
        aoff[i] = (m0 + row) * K + s * 8;
        boff[i] = (n0 + row) * K + s * 8;
        ldsoff[i] = idx * 16;
    }

    f32x4 acc[8][4] = {};

#pragma unroll
    for (int kh = 0; kh < 2; ++kh) {
        if (kh == 0) {
#pragma unroll
            for (int i = 0; i < 2; ++i) gll16(A + aoff[i], smem + ldsoff[i]);
#pragma unroll
            for (int i = 0; i < 2; ++i) gll16(Bt + boff[i], smem + 65536 + ldsoff[i]);
        } else {
#pragma unroll
            for (int i = 0; i < 2; ++i) gll16(A + aoff[i] + 32, smem + 16384 + ldsoff[i]);
#pragma unroll
            for (int i = 0; i < 2; ++i) gll16(Bt + boff[i] + 32, smem + 65536 + 16384 + ldsoff[i]);
        }
    }

    for (int kb = 0; kb < NT; ++kb) {
        const int c = kb & 1;
        const int kn = (kb + 1 < NT) ? kb + 1 : NT - 1;
        const int cn = c ^ 1;
        const int Abase = c * 32768;
        const int Bbase = 65536 + c * 32768;
        const int AbaseN = cn * 32768;
        const int BbaseN = 65536 + cn * 32768;

        bf16x8 bf[4], af[4];

#pragma unroll
        for (int ph = 0; ph < 4; ++ph) {
            const int kk = ph >> 1;
            const int mb = (ph & 1) * 4;

            if ((ph & 1) == 0) {
                asm volatile("s_waitcnt vmcnt(4)" ::: "memory");
            }
            __builtin_amdgcn_s_barrier();
            __builtin_amdgcn_sched_barrier(0);

            if ((ph & 1) == 0) {
#pragma unroll
                for (int nf = 0; nf < 4; ++nf) {
                    const int row = wn * 64 + nf * 16 + (l & 15);
                    const int byte = Bbase + kk * 16384 + row * 64 +
                                     ((((l >> 4) + row + (row >> 2)) & 3) * 16);
                    bf[nf] = *reinterpret_cast<const bf16x8*>(smem + byte);
                }
            }
#pragma unroll
            for (int mfl = 0; mfl < 4; ++mfl) {
                const int row = wm * 128 + (mb + mfl) * 16 + (l & 15);
                const int byte = Abase + kk * 16384 + row * 64 +
                                 ((((l >> 4) + row + (row >> 2)) & 3) * 16);
                af[mfl] = *reinterpret_cast<const bf16x8*>(smem + byte);
            }

            {
                const int khs = ph >> 1;
                if ((ph & 1) == 0) {
#pragma unroll
                    for (int i = 0; i < 2; ++i)
                        gll16(A + aoff[i] + kn * 64 + khs * 32,
                              smem + AbaseN + khs * 16384 + ldsoff[i]);
                } else {
#pragma unroll
                    for (int i = 0; i < 2; ++i)
                        gll16(Bt + boff[i] + kn * 64 + khs * 32,
                              smem + BbaseN + khs * 16384 + ldsoff[i]);
                }
            }

            asm volatile("s_waitcnt lgkmcnt(0)" ::: "memory");
            __builtin_amdgcn_sched_barrier(0);
            __builtin_amdgcn_s_setprio(1);
#pragma unroll
            for (int mfl = 0; mfl < 4; ++mfl)
#pragma unroll
                for (int nf = 0; nf < 4; ++nf)
                    acc[mb + mfl][nf] = __builtin_amdgcn_mfma_f32_16x16x32_bf16(
                        af[mfl], bf[nf], acc[mb + mfl][nf], 0, 0, 0);
            __builtin_amdgcn_s_setprio(0);
        }
    }

    asm volatile("s_waitcnt vmcnt(0)" ::: "memory");

    if (z < 2) {
        unsigned short* outz = qkv + (size_t)z * NTOKn * Dn;
#pragma unroll
        for (int mf = 0; mf < 8; ++mf) {
            const int row = m0 + wm * 128 + mf * 16 + (l >> 4) * 4;
#pragma unroll
            for (int nf = 0; nf < 4; ++nf) {
                const int col = (n0 + wn * 64 + nf * 16 + (l & 15)) & 1023;
#pragma unroll
                for (int i = 0; i < 4; ++i)
                    outz[(size_t)(row + i) * Dn + col] = f2bf(acc[mf][nf][i] + biasv[nf]);
            }
        }
    } else {
        // V: write transposed vT[(b*1024 + col)][s], 4 consecutive s per lane
#pragma unroll
        for (int mf = 0; mf < 8; ++mf) {
            const int row = m0 + wm * 128 + mf * 16 + (l >> 4) * 4;
            const int b = row >> 11, s = row & 2047;
#pragma unroll
            for (int nf = 0; nf < 4; ++nf) {
                const int col = (n0 + wn * 64 + nf * 16 + (l & 15)) & 1023;
                ushort4 o;
                o.x = f2bf(acc[mf][nf][0] + biasv[nf]);
                o.y = f2bf(acc[mf][nf][1] + biasv[nf]);
                o.z = f2bf(acc[mf][nf][2] + biasv[nf]);
                o.w = f2bf(acc[mf][nf][3] + biasv[nf]);
                *reinterpret_cast<ushort4*>(vT + ((size_t)(b * 1024 + col)) * Sn + s) = o;
            }
        }
    }
}

// ---------------- bf16 GEMM (m97 structure, 128x128) for the out-projection ----------------
__global__ __launch_bounds__(256) void k_gemm_op(const unsigned short* __restrict__ A,
                                                 const unsigned short* __restrict__ Bt,
                                                 const float* __restrict__ bias,
                                                 float* __restrict__ C,
                                                 int M, int N, int K) {
    __shared__ unsigned short As[128][32];
    __shared__ unsigned short Bs[128][32];
    const int t = threadIdx.x;
    const int w = t >> 6, l = t & 63;
    const int m0 = blockIdx.x * 128, n0 = blockIdx.y * 128;
    const int wr = (w >> 1) * 64, wc = (w & 1) * 64;

    const int lrow = t >> 2;
    const int lcol = (t & 3) * 8;
    const unsigned short* gA = A + (size_t)(m0 + lrow) * K + lcol;
    const unsigned short* gB = Bt + (size_t)(n0 + lrow) * K + lcol;
    unsigned short* lA = &As[0][0] + t * 8;
    unsigned short* lB = &Bs[0][0] + t * 8;

    f32x4 acc[4][4] = {};

    for (int k0 = 0; k0 < K; k0 += 32) {
        __syncthreads();
        gll16(gA + k0, lA);
        gll16(gA + (size_t)64 * K + k0, lA + 2048);
        gll16(gB + k0, lB);
        gll16(gB + (size_t)64 * K + k0, lB + 2048);
        __syncthreads();

        bf16x8 af[4], bfv[4];
#pragma unroll
        for (int i = 0; i < 4; ++i)
            af[i] = *reinterpret_cast<const bf16x8*>(&As[wr + i * 16 + (l & 15)][(l >> 4) * 8]);
#pragma unroll
        for (int i = 0; i < 4; ++i)
            bfv[i] = *reinterpret_cast<const bf16x8*>(&Bs[wc + i * 16 + (l & 15)][(l >> 4) * 8]);
#pragma unroll
        for (int mi = 0; mi < 4; ++mi)
#pragma unroll
            for (int ni = 0; ni < 4; ++ni)
                acc[mi][ni] =
                    __builtin_amdgcn_mfma_f32_16x16x32_bf16(af[mi], bfv[ni], acc[mi][ni], 0, 0, 0);
    }

#pragma unroll
    for (int mi = 0; mi < 4; ++mi) {
        const int row = m0 + wr + mi * 16 + (l >> 4) * 4;
#pragma unroll
        for (int ni = 0; ni < 4; ++ni) {
            const int col = n0 + wc + ni * 16 + (l & 15);
            const float bv = bias[col];
#pragma unroll
            for (int i = 0; i < 4; ++i)
                C[(size_t)(row + i) * N + col] = acc[mi][ni][i] + bv;
        }
    }
}

// ---------------- fused attention: attn = relu(QK^T*scale), ctx = attn @ V ----------------
// FULL-LINE attn stores: relu'd f32 P staged in per-wave LDS Pf[32][132], then
// stored as 16x global_store_dwordx4 per wave-iter, each covering a contiguous
// 128B-aligned 1 KB (8 full L2 lines) -> no partial-line write-allocate (RFO).
// PV's bf16 fragments are rebuilt from the same f32 LDS (identical numerics).
// Counted vmcnt(16): per iter 8 gll loads (oldest) + 16 stores; <=16 outstanding
// guarantees loads landed, stores never drained in-loop (T4).
__global__ __launch_bounds__(256, 1) void k_attn(const unsigned short* __restrict__ Qb,
                                                 const unsigned short* __restrict__ Kb,
                                                 const unsigned short* __restrict__ VTb,
                                                 float* __restrict__ attn,
                                                 unsigned short* __restrict__ ctx) {
    __shared__ unsigned short Ks[128 * 64];
    __shared__ unsigned short Vs[64 * 128];
    __shared__ float Pf[4][32 * 132];  // per-wave f32 P (relu'd, scaled), +4 pad

    const int t = threadIdx.x;
    const int w = t >> 6, l = t & 63;

    // XCD-aware bijective remap (dispatch round-robins linear%8 across XCDs)
    const int lin = blockIdx.x + 16 * blockIdx.y;
    const int xcd = lin & 7, idx = lin >> 3;
    const int bh = xcd * 4 + (idx >> 4);
    const int q0 = (idx & 15) * 128;
    const int b = bh >> 4, h = bh & 15;
    const float scale = 0.125f;  // 1/sqrt(64)

    bf16x8 qf[2][2];
#pragma unroll
    for (int mi = 0; mi < 2; ++mi)
#pragma unroll
        for (int kk = 0; kk < 2; ++kk)
            qf[mi][kk] = *reinterpret_cast<const bf16x8*>(
                Qb + (size_t)(b * Sn + q0 + w * 32 + mi * 16 + (l & 15)) * Dn + h * DEP +
                kk * 32 + (l >> 4) * 8);

    const int krow = t >> 3;
    const int kcolswz = ((t & 7) * 8) ^ ((krow & 7) << 3);
    const int vrow = t >> 4;
    const int vcolswz = ((t & 15) * 8) ^ ((vrow & 7) << 3);
    unsigned short* lK = Ks + t * 8;
    unsigned short* lV = Vs + t * 8;

    f32x4 ctxa[2][4] = {};
    float* const abase = attn + (size_t)bh * Sn * Sn + (size_t)(q0 + w * 32) * Sn;

    auto STAGE = [&](int kb) {
#pragma unroll
        for (int is = 0; is < 4; ++is) {
            gll16(Kb + (size_t)(b * Sn + kb * 128 + is * 32 + krow) * Dn + h * DEP + kcolswz,
                  lK + is * 2048);
            gll16(VTb + (size_t)(bh * DEP + is * 16 + vrow) * Sn + kb * 128 + vcolswz,
                  lV + is * 2048);
        }
    };

    // QK^T -> relu/scale -> f32 into per-wave Pf
    auto QKT = [&]() {
        f32x4 sa[2][8];
#pragma unroll
        for (int mi = 0; mi < 2; ++mi)
#pragma unroll
            for (int nj = 0; nj < 8; ++nj)
                sa[mi][nj] = (f32x4){0.f, 0.f, 0.f, 0.f};
#pragma unroll
        for (int nj = 0; nj < 8; ++nj) {
            const int kr = nj * 16 + (l & 15);
#pragma unroll
            for (int kk = 0; kk < 2; ++kk) {
                const int kidx = (kr * 64 + kk * 32 + (l >> 4) * 8) ^ ((kr & 7) << 3);
                const bf16x8 bfr = *reinterpret_cast<const bf16x8*>(Ks + kidx);
                sa[0][nj] = __builtin_amdgcn_mfma_f32_16x16x32_bf16(qf[0][kk], bfr, sa[0][nj], 0, 0, 0);
                sa[1][nj] = __builtin_amdgcn_mfma_f32_16x16x32_bf16(qf[1][kk], bfr, sa[1][nj], 0, 0, 0);
            }
        }
#pragma unroll
        for (int mi = 0; mi < 2; ++mi) {
#pragma unroll
            for (int nj = 0; nj < 8; ++nj) {
                const int kc = nj * 16 + (l & 15);
#pragma unroll
                for (int i = 0; i < 4; ++i) {
                    float p = sa[mi][nj][i] * scale;
                    p = p > 0.f ? p : 0.f;
                    Pf[w][(mi * 16 + (l >> 4) * 4 + i) * 132 + kc] = p;
                }
            }
        }
    };

    // ctx += P @ V, P fragments rebuilt (f32->bf16) from Pf
    auto PV = [&]() {
        bf16x8 pf[2][4];
#pragma unroll
        for (int mi = 0; mi < 2; ++mi)
#pragma unroll
            for (int kk = 0; kk < 4; ++kk) {
                const int base = (mi * 16 + (l & 15)) * 132 + kk * 32 + (l >> 4) * 8;
                f32x4 a = *reinterpret_cast<const f32x4*>(&Pf[w][base]);
                f32x4 bb = *reinterpret_cast<const f32x4*>(&Pf[w][base + 4]);
                union { unsigned short us[8]; bf16x8 v; } pk;
#pragma unroll
                for (int e = 0; e < 4; ++e) {
                    pk.us[e] = f2bf(a[e]);
                    pk.us[4 + e] = f2bf(bb[e]);
                }
                pf[mi][kk] = pk.v;
            }
#pragma unroll
        for (int nd = 0; nd < 4; ++nd) {
            const int vr = nd * 16 + (l & 15);
#pragma unroll
            for (int kk = 0; kk < 4; ++kk) {
                const int vidx = (vr * 128 + kk * 32 + (l >> 4) * 8) ^ ((vr & 7) << 3);
                const bf16x8 vfr = *reinterpret_cast<const bf16x8*>(Vs + vidx);
                ctxa[0][nd] = __builtin_amdgcn_mfma_f32_16x16x32_bf16(pf[0][kk], vfr, ctxa[0][nd], 0, 0, 0);
                ctxa[1][nd] = __builtin_amdgcn_mfma_f32_16x16x32_bf16(pf[1][kk], vfr, ctxa[1][nd], 0, 0, 0);
            }
        }
    };

    // 16 x dwordx4 per wave: instruction j writes rows (2j,2j+1) x 512B each
    // -> contiguous 1 KB, 128B-aligned: full-line writes only.
    auto STORE_ATTN = [&](int kb) {
        float* arow = abase + kb * 128;
        const int r = l >> 5, c4 = (l & 31) * 4;
#pragma unroll
        for (int j = 0; j < 16; ++j) {
            const int row = 2 * j + r;
            f32x4 v = *reinterpret_cast<const f32x4*>(&Pf[w][row * 132 + c4]);
            *reinterpret_cast<f32x4*>(arow + (size_t)row * Sn + c4) = v;
        }
    };

    // ---- peeled iteration 0 ----
    STAGE(0);
    asm volatile("s_waitcnt vmcnt(0)" ::: "memory");
    __builtin_amdgcn_s_barrier();
    __builtin_amdgcn_sched_barrier(0);
    QKT();
    PV();

    for (int kb = 1; kb < Sn / 128; ++kb) {
        asm volatile("s_waitcnt lgkmcnt(0)" ::: "memory");
        __builtin_amdgcn_s_barrier();
        __builtin_amdgcn_sched_barrier(0);
        STAGE(kb);                             // 8 loads (oldest)
        asm volatile("" ::: "memory");         // keep stores after loads in issue order
        STORE_ATTN(kb - 1);                    // 16 full-line stores
        asm volatile("s_waitcnt vmcnt(16)" ::: "memory");  // loads retired, stores in flight
        __builtin_amdgcn_s_barrier();
        __builtin_amdgcn_sched_barrier(0);
        QKT();
        PV();
    }
    STORE_ATTN(Sn / 128 - 1);

    // ---- store ctx (bf16, head-concat layout [B*S][D]) ----
#pragma unroll
    for (int mi = 0; mi < 2; ++mi) {
#pragma unroll
        for (int nd = 0; nd < 4; ++nd) {
            const int dc = nd * 16 + (l & 15);
#pragma unroll
            for (int i = 0; i < 4; ++i) {
                const int qr = q0 + w * 32 + mi * 16 + (l >> 4) * 4 + i;
                ctx[(size_t)(b * Sn + qr) * Dn + h * DEP + dc] = f2bf(ctxa[mi][nd][i]);
            }
        }
    }
}

extern "C" void kernel_launch(void* const* d_in, const int* in_sizes, int n_in,
                              void* d_out, int out_size, void* d_ws, size_t ws_size,
                              hipStream_t stream) {
    (void)in_sizes; (void)n_in; (void)out_size; (void)ws_size;
    const float* x  = (const float*)d_in[0];
    const float* wq = (const float*)d_in[1];
    const float* bq = (const float*)d_in[2];
    const float* wk = (const float*)d_in[3];
    const float* bk = (const float*)d_in[4];
    const float* wv = (const float*)d_in[5];
    const float* bv = (const float*)d_in[6];
    const float* wo = (const float*)d_in[7];
    const float* bo = (const float*)d_in[8];

    float* out  = (float*)d_out;
    float* attn = out + (size_t)Bn * Sn * Dn;  // outputs concatenated: (out, attn)

    char* ws = (char*)d_ws;
    unsigned short* xb = (unsigned short*)ws;  ws += (size_t)NTOKn * Dn * 2;       // 8 MB
    unsigned short* wT = (unsigned short*)ws;  ws += (size_t)4 * Dn * Dn * 2;      // 8 MB [q,k,v,o]
    unsigned short* qkv = (unsigned short*)ws; ws += (size_t)3 * NTOKn * Dn * 2;   // 24 MB (v third unused)
    unsigned short* vT = (unsigned short*)ws;  ws += (size_t)NTOKn * Dn * 2;       // 8 MB
    unsigned short* ctx = (unsigned short*)ws;                                     // 8 MB

    const size_t DD = (size_t)Dn * Dn;

    static bool attr_set = false;
    if (!attr_set) {
        hipFuncSetAttribute(reinterpret_cast<const void*>(k_qkv8),
                            hipFuncAttributeMaxDynamicSharedMemorySize, 131072);
        attr_set = true;
    }

    k_prep<<<dim3(5120), 256, 0, stream>>>(x, wq, wk, wv, wo, xb,
                                           wT, wT + DD, wT + 2 * DD, wT + 3 * DD);
    k_qkv8<<<dim3(16, 12), 512, 131072, stream>>>(xb, wT, bq, bk, bv, qkv, vT);
    k_attn<<<dim3(16, 32), 256, 0, stream>>>(qkv, qkv + (size_t)NTOKn * Dn, vT, attn, ctx);
    k_gemm_op<<<dim3(32, 8), 256, 0, stream>>>(ctx, wT + 3 * DD, bo, out, NTOKn, Dn, Dn);
}

// Round 9
// 227.668 us; speedup vs baseline: 1.0661x; 1.0661x over previous
//
#include <hip/hip_runtime.h>
#include <hip/hip_bf16.h>

// Problem constants (reference: B=2, S=2048, D=1024, H=16, DEPTH=64)
constexpr int Bn = 2, Sn = 2048, Dn = 1024, Hn = 16, DEP = 64;
constexpr int NTOKn = Bn * Sn;  // 4096 rows for the token-dim GEMMs

typedef __bf16 bf16x8 __attribute__((ext_vector_type(8)));
typedef float f32x4 __attribute__((ext_vector_type(4)));

__device__ __forceinline__ unsigned short f2bf(float f) {
    union { __hip_bfloat16 h; unsigned short u; } cv;
    cv.h = __float2bfloat16(f);
    return cv.u;
}

// async global->LDS, 16B per lane. LDS dest must be wave-uniform base + lane*16.
__device__ __forceinline__ void gll16(const void* g, void* l) {
    __builtin_amdgcn_global_load_lds(
        (const __attribute__((address_space(1))) unsigned int*)g,
        (__attribute__((address_space(3))) unsigned int*)l, 16, 0, 0);
}

// ---------------- fused prep: x f32->bf16 convert + 4x weight transpose ----------------
__global__ __launch_bounds__(256) void k_prep(const float* __restrict__ x,
                                              const float* __restrict__ w0,
                                              const float* __restrict__ w1,
                                              const float* __restrict__ w2,
                                              const float* __restrict__ w3,
                                              unsigned short* __restrict__ xb,
                                              unsigned short* __restrict__ t0,
                                              unsigned short* __restrict__ t1,
                                              unsigned short* __restrict__ t2,
                                              unsigned short* __restrict__ t3) {
    const int bid = blockIdx.x;
    const int t = threadIdx.x;
    if (bid < 4096) {
        const int idx = (bid * 256 + t) * 4;
        float4 v = *reinterpret_cast<const float4*>(x + idx);
        ushort4 o;
        o.x = f2bf(v.x); o.y = f2bf(v.y); o.z = f2bf(v.z); o.w = f2bf(v.w);
        *reinterpret_cast<ushort4*>(xb + idx) = o;
        return;
    }
    const int b2 = bid - 4096;
    const float* w; unsigned short* tp;
    switch (b2 >> 8) {
        case 0: w = w0; tp = t0; break;
        case 1: w = w1; tp = t1; break;
        case 2: w = w2; tp = t2; break;
        default: w = w3; tp = t3; break;
    }
    __shared__ unsigned short tile[64][65];
    const int k0 = ((b2 & 255) >> 4) * 64, n0 = (b2 & 15) * 64;
    const int c = t & 63, rb = t >> 6;
#pragma unroll
    for (int i = 0; i < 16; ++i) {
        int r = rb + i * 4;
        tile[r][c] = f2bf(w[(size_t)(k0 + r) * Dn + n0 + c]);
    }
    __syncthreads();
#pragma unroll
    for (int i = 0; i < 16; ++i) {
        int n = rb + i * 4;
        tp[(size_t)(n0 + n) * Dn + k0 + c] = tile[c][n];
    }
}

// =================== QKV GEMM, 8-phase-style 256x256 tile ===================
// (counted vmcnt(4), T2 slot-swizzle, T5 setprio)
// Epilogue: Q/K blocks write qkv[z][token][dim]; V blocks (z==2) write the
// TRANSPOSED vT[(b*1024+col)][s] directly as ushort4.
__global__ __launch_bounds__(512, 2) void k_qkv8(const unsigned short* __restrict__ A,
                                                 const unsigned short* __restrict__ Bt,
                                                 const float* __restrict__ bq,
                                                 const float* __restrict__ bk,
                                                 const float* __restrict__ bv,
                                                 unsigned short* __restrict__ qkv,
                                                 unsigned short* __restrict__ vT) {
    extern __shared__ char smem[];  // 131072 bytes
    constexpr int K = 1024, NT = K / 64;  // 16 K-steps

    const int t = threadIdx.x;
    const int w = t >> 6, l = t & 63;
    const int wm = w >> 2, wn = w & 3;
    const int m0 = blockIdx.x * 256;
    const int n0 = blockIdx.y * 256;
    const int z = n0 >> 10;

    const float* bias = (z == 0) ? bq : (z == 1 ? bk : bv);
    float biasv[4];
#pragma unroll
    for (int nf = 0; nf < 4; ++nf)
        biasv[nf] = bias[(n0 + wn * 64 + nf * 16 + (l & 15)) & 1023];

    int aoff[2], boff[2], ldsoff[2];
#pragma unroll
    for (int i = 0; i < 2; ++i) {
        const int idx = i * 512 + t;
        const int row = idx >> 2;
        const int s = ((idx & 3) - row - (row >> 2)) & 3;
        aoff[i] = (m0 + row) * K + s * 8;
        boff[i] = (n0 + row) * K + s * 8;
        ldsoff[i] = idx * 16;
    }

    f32x4 acc[8][4] = {};

#pragma unroll
    for (int kh = 0; kh < 2; ++kh) {
        if (kh == 0) {
#pragma unroll
            for (int i = 0; i < 2; ++i) gll16(A + aoff[i], smem + ldsoff[i]);
#pragma unroll
            for (int i = 0; i < 2; ++i) gll16(Bt + boff[i], smem + 65536 + ldsoff[i]);
        } else {
#pragma unroll
            for (int i = 0; i < 2; ++i) gll16(A + aoff[i] + 32, smem + 16384 + ldsoff[i]);
#pragma unroll
            for (int i = 0; i < 2; ++i) gll16(Bt + boff[i] + 32, smem + 65536 + 16384 + ldsoff[i]);
        }
    }

    for (int kb = 0; kb < NT; ++kb) {
        const int c = kb & 1;
        const int kn = (kb + 1 < NT) ? kb + 1 : NT - 1;
        const int cn = c ^ 1;
        const int Abase = c * 32768;
        const int Bbase = 65536 + c * 32768;
        const int AbaseN = cn * 32768;
        const int BbaseN = 65536 + cn * 32768;

        bf16x8 bf[4], af[4];

#pragma unroll
        for (int ph = 0; ph < 4; ++ph) {
            const int kk = ph >> 1;
            const int mb = (ph & 1) * 4;

            if ((ph & 1) == 0) {
                asm volatile("s_waitcnt vmcnt(4)" ::: "memory");
            }
            __builtin_amdgcn_s_barrier();
            __builtin_amdgcn_sched_barrier(0);

            if ((ph & 1) == 0) {
#pragma unroll
                for (int nf = 0; nf < 4; ++nf) {
                    const int row = wn * 64 + nf * 16 + (l & 15);
                    const int byte = Bbase + kk * 16384 + row * 64 +
                                     ((((l >> 4) + row + (row >> 2)) & 3) * 16);
                    bf[nf] = *reinterpret_cast<const bf16x8*>(smem + byte);
                }
            }
#pragma unroll
            for (int mfl = 0; mfl < 4; ++mfl) {
                const int row = wm * 128 + (mb + mfl) * 16 + (l & 15);
                const int byte = Abase + kk * 16384 + row * 64 +
                                 ((((l >> 4) + row + (row >> 2)) & 3) * 16);
                af[mfl] = *reinterpret_cast<const bf16x8*>(smem + byte);
            }

            {
                const int khs = ph >> 1;
                if ((ph & 1) == 0) {
#pragma unroll
                    for (int i = 0; i < 2; ++i)
                        gll16(A + aoff[i] + kn * 64 + khs * 32,
                              smem + AbaseN + khs * 16384 + ldsoff[i]);
                } else {
#pragma unroll
                    for (int i = 0; i < 2; ++i)
                        gll16(Bt + boff[i] + kn * 64 + khs * 32,
                              smem + BbaseN + khs * 16384 + ldsoff[i]);
                }
            }

            asm volatile("s_waitcnt lgkmcnt(0)" ::: "memory");
            __builtin_amdgcn_sched_barrier(0);
            __builtin_amdgcn_s_setprio(1);
#pragma unroll
            for (int mfl = 0; mfl < 4; ++mfl)
#pragma unroll
                for (int nf = 0; nf < 4; ++nf)
                    acc[mb + mfl][nf] = __builtin_amdgcn_mfma_f32_16x16x32_bf16(
                        af[mfl], bf[nf], acc[mb + mfl][nf], 0, 0, 0);
            __builtin_amdgcn_s_setprio(0);
        }
    }

    asm volatile("s_waitcnt vmcnt(0)" ::: "memory");

    if (z < 2) {
        unsigned short* outz = qkv + (size_t)z * NTOKn * Dn;
#pragma unroll
        for (int mf = 0; mf < 8; ++mf) {
            const int row = m0 + wm * 128 + mf * 16 + (l >> 4) * 4;
#pragma unroll
            for (int nf = 0; nf < 4; ++nf) {
                const int col = (n0 + wn * 64 + nf * 16 + (l & 15)) & 1023;
#pragma unroll
                for (int i = 0; i < 4; ++i)
                    outz[(size_t)(row + i) * Dn + col] = f2bf(acc[mf][nf][i] + biasv[nf]);
            }
        }
    } else {
        // V: write transposed vT[(b*1024 + col)][s], 4 consecutive s per lane
#pragma unroll
        for (int mf = 0; mf < 8; ++mf) {
            const int row = m0 + wm * 128 + mf * 16 + (l >> 4) * 4;
            const int b = row >> 11, s = row & 2047;
#pragma unroll
            for (int nf = 0; nf < 4; ++nf) {
                const int col = (n0 + wn * 64 + nf * 16 + (l & 15)) & 1023;
                ushort4 o;
                o.x = f2bf(acc[mf][nf][0] + biasv[nf]);
                o.y = f2bf(acc[mf][nf][1] + biasv[nf]);
                o.z = f2bf(acc[mf][nf][2] + biasv[nf]);
                o.w = f2bf(acc[mf][nf][3] + biasv[nf]);
                *reinterpret_cast<ushort4*>(vT + ((size_t)(b * 1024 + col)) * Sn + s) = o;
            }
        }
    }
}

// ---------------- bf16 GEMM (m97 structure, 128x128) for the out-projection ----------------
__global__ __launch_bounds__(256) void k_gemm_op(const unsigned short* __restrict__ A,
                                                 const unsigned short* __restrict__ Bt,
                                                 const float* __restrict__ bias,
                                                 float* __restrict__ C,
                                                 int M, int N, int K) {
    __shared__ unsigned short As[128][32];
    __shared__ unsigned short Bs[128][32];
    const int t = threadIdx.x;
    const int w = t >> 6, l = t & 63;
    const int m0 = blockIdx.x * 128, n0 = blockIdx.y * 128;
    const int wr = (w >> 1) * 64, wc = (w & 1) * 64;

    const int lrow = t >> 2;
    const int lcol = (t & 3) * 8;
    const unsigned short* gA = A + (size_t)(m0 + lrow) * K + lcol;
    const unsigned short* gB = Bt + (size_t)(n0 + lrow) * K + lcol;
    unsigned short* lA = &As[0][0] + t * 8;
    unsigned short* lB = &Bs[0][0] + t * 8;

    f32x4 acc[4][4] = {};

    for (int k0 = 0; k0 < K; k0 += 32) {
        __syncthreads();
        gll16(gA + k0, lA);
        gll16(gA + (size_t)64 * K + k0, lA + 2048);
        gll16(gB + k0, lB);
        gll16(gB + (size_t)64 * K + k0, lB + 2048);
        __syncthreads();

        bf16x8 af[4], bfv[4];
#pragma unroll
        for (int i = 0; i < 4; ++i)
            af[i] = *reinterpret_cast<const bf16x8*>(&As[wr + i * 16 + (l & 15)][(l >> 4) * 8]);
#pragma unroll
        for (int i = 0; i < 4; ++i)
            bfv[i] = *reinterpret_cast<const bf16x8*>(&Bs[wc + i * 16 + (l & 15)][(l >> 4) * 8]);
#pragma unroll
        for (int mi = 0; mi < 4; ++mi)
#pragma unroll
            for (int ni = 0; ni < 4; ++ni)
                acc[mi][ni] =
                    __builtin_amdgcn_mfma_f32_16x16x32_bf16(af[mi], bfv[ni], acc[mi][ni], 0, 0, 0);
    }

#pragma unroll
    for (int mi = 0; mi < 4; ++mi) {
        const int row = m0 + wr + mi * 16 + (l >> 4) * 4;
#pragma unroll
        for (int ni = 0; ni < 4; ++ni) {
            const int col = n0 + wc + ni * 16 + (l & 15);
            const float bv = bias[col];
#pragma unroll
            for (int i = 0; i < 4; ++i)
                C[(size_t)(row + i) * N + col] = acc[mi][ni][i] + bv;
        }
    }
}

// ---------------- fused attention: attn = relu(QK^T*scale), ctx = attn @ V ----------------
// SWAPPED QK^T: sa[mi][nj] = mfma(K_frag, Q_frag) -> lane holds q-row (l&15)
// and 4 CONSECUTIVE k-cols ((l>>4)*4+i). attn stores become 16x dwordx4 from
// registers (was 64x scalar dword); P->LDS becomes 16x ds_write_b64 (was 64x
// b16). PV unchanged (reads Ps). LDS 67KB -> 2 blocks/CU. Counted vmcnt(16).
__global__ __launch_bounds__(256, 2) void k_attn(const unsigned short* __restrict__ Qb,
                                                 const unsigned short* __restrict__ Kb,
                                                 const unsigned short* __restrict__ VTb,
                                                 float* __restrict__ attn,
                                                 unsigned short* __restrict__ ctx) {
    __shared__ unsigned short Ks[128 * 64];
    __shared__ unsigned short Vs[64 * 128];
    __shared__ unsigned short Ps[4][32][136];

    const int t = threadIdx.x;
    const int w = t >> 6, l = t & 63;

    // XCD-aware bijective remap (dispatch round-robins linear%8 across XCDs)
    const int lin = blockIdx.x + 16 * blockIdx.y;
    const int xcd = lin & 7, idx = lin >> 3;
    const int bh = xcd * 4 + (idx >> 4);
    const int q0 = (idx & 15) * 128;
    const int b = bh >> 4, h = bh & 15;
    const float scale = 0.125f;  // 1/sqrt(64)

    bf16x8 qf[2][2];
#pragma unroll
    for (int mi = 0; mi < 2; ++mi)
#pragma unroll
        for (int kk = 0; kk < 2; ++kk)
            qf[mi][kk] = *reinterpret_cast<const bf16x8*>(
                Qb + (size_t)(b * Sn + q0 + w * 32 + mi * 16 + (l & 15)) * Dn + h * DEP +
                kk * 32 + (l >> 4) * 8);

    const int krow = t >> 3;
    const int kcolswz = ((t & 7) * 8) ^ ((krow & 7) << 3);
    const int vrow = t >> 4;
    const int vcolswz = ((t & 15) * 8) ^ ((vrow & 7) << 3);
    unsigned short* lK = Ks + t * 8;
    unsigned short* lV = Vs + t * 8;

    f32x4 ctxa[2][4] = {};
    f32x4 sa[2][8];  // swapped layout: q-row = l&15, k-cols = nj*16 + (l>>4)*4 + i

    float* const abase = attn + (size_t)bh * Sn * Sn + (size_t)(q0 + w * 32) * Sn;

    auto STAGE = [&](int kb) {
#pragma unroll
        for (int is = 0; is < 4; ++is) {
            gll16(Kb + (size_t)(b * Sn + kb * 128 + is * 32 + krow) * Dn + h * DEP + kcolswz,
                  lK + is * 2048);
            gll16(VTb + (size_t)(bh * DEP + is * 16 + vrow) * Sn + kb * 128 + vcolswz,
                  lV + is * 2048);
        }
    };

    // Swapped QK^T -> relu/scale in regs -> P (bf16) to per-wave LDS via b64 writes
    auto QKT = [&]() {
#pragma unroll
        for (int mi = 0; mi < 2; ++mi)
#pragma unroll
            for (int nj = 0; nj < 8; ++nj)
                sa[mi][nj] = (f32x4){0.f, 0.f, 0.f, 0.f};
#pragma unroll
        for (int nj = 0; nj < 8; ++nj) {
            const int kr = nj * 16 + (l & 15);
#pragma unroll
            for (int kk = 0; kk < 2; ++kk) {
                const int kidx = (kr * 64 + kk * 32 + (l >> 4) * 8) ^ ((kr & 7) << 3);
                const bf16x8 kfr = *reinterpret_cast<const bf16x8*>(Ks + kidx);
                // swapped: K as A, Q as B -> D[row=k-col-quad][col=q-row]
                sa[0][nj] = __builtin_amdgcn_mfma_f32_16x16x32_bf16(kfr, qf[0][kk], sa[0][nj], 0, 0, 0);
                sa[1][nj] = __builtin_amdgcn_mfma_f32_16x16x32_bf16(kfr, qf[1][kk], sa[1][nj], 0, 0, 0);
            }
        }
#pragma unroll
        for (int mi = 0; mi < 2; ++mi) {
            const int prow = mi * 16 + (l & 15);
            const int pcol = (l >> 4) * 4;
#pragma unroll
            for (int nj = 0; nj < 8; ++nj) {
                f32x4 v = sa[mi][nj];
#pragma unroll
                for (int i = 0; i < 4; ++i) {
                    float p = v[i] * scale;
                    v[i] = p > 0.f ? p : 0.f;
                }
                sa[mi][nj] = v;
                ushort4 pk;
                pk.x = f2bf(v[0]); pk.y = f2bf(v[1]); pk.z = f2bf(v[2]); pk.w = f2bf(v[3]);
                *reinterpret_cast<ushort4*>(&Ps[w][prow & 31][nj * 16 + pcol]) = pk;
            }
        }
    };

    auto PV = [&]() {
        bf16x8 pf[2][4];
#pragma unroll
        for (int mi = 0; mi < 2; ++mi)
#pragma unroll
            for (int kk = 0; kk < 4; ++kk)
                pf[mi][kk] = *reinterpret_cast<const bf16x8*>(
                    &Ps[w][mi * 16 + (l & 15)][kk * 32 + (l >> 4) * 8]);
#pragma unroll
        for (int nd = 0; nd < 4; ++nd) {
            const int vr = nd * 16 + (l & 15);
#pragma unroll
            for (int kk = 0; kk < 4; ++kk) {
                const int vidx = (vr * 128 + kk * 32 + (l >> 4) * 8) ^ ((vr & 7) << 3);
                const bf16x8 vfr = *reinterpret_cast<const bf16x8*>(Vs + vidx);
                ctxa[0][nd] = __builtin_amdgcn_mfma_f32_16x16x32_bf16(pf[0][kk], vfr, ctxa[0][nd], 0, 0, 0);
                ctxa[1][nd] = __builtin_amdgcn_mfma_f32_16x16x32_bf16(pf[1][kk], vfr, ctxa[1][nd], 0, 0, 0);
            }
        }
    };

    // 16x global_store_dwordx4 from registers: lane writes its 4 consecutive
    // k-cols; per instruction 16 rows x 64B contiguous chunks.
    auto STORE_SA = [&](int kb) {
        float* arow = abase + kb * 128;
#pragma unroll
        for (int mi = 0; mi < 2; ++mi) {
            float* rp = arow + (size_t)(mi * 16 + (l & 15)) * Sn + (l >> 4) * 4;
#pragma unroll
            for (int nj = 0; nj < 8; ++nj)
                *reinterpret_cast<f32x4*>(rp + nj * 16) = sa[mi][nj];
        }
    };

    STAGE(0);
    asm volatile("s_waitcnt vmcnt(0)" ::: "memory");
    __builtin_amdgcn_s_barrier();
    __builtin_amdgcn_sched_barrier(0);
    QKT();
    PV();

    for (int kb = 1; kb < Sn / 128; ++kb) {
        asm volatile("s_waitcnt lgkmcnt(0)" ::: "memory");
        __builtin_amdgcn_s_barrier();
        __builtin_amdgcn_sched_barrier(0);
        STAGE(kb);                             // 8 loads (oldest)
        asm volatile("" ::: "memory");         // keep stores after loads in issue order
        STORE_SA(kb - 1);                      // 16 dwordx4 stores (fire and forget)
        asm volatile("s_waitcnt vmcnt(16)" ::: "memory");  // loads retired, stores free
        __builtin_amdgcn_s_barrier();
        __builtin_amdgcn_sched_barrier(0);
        QKT();
        PV();
    }
    STORE_SA(Sn / 128 - 1);

#pragma unroll
    for (int mi = 0; mi < 2; ++mi) {
#pragma unroll
        for (int nd = 0; nd < 4; ++nd) {
            const int dc = nd * 16 + (l & 15);
#pragma unroll
            for (int i = 0; i < 4; ++i) {
                const int qr = q0 + w * 32 + mi * 16 + (l >> 4) * 4 + i;
                ctx[(size_t)(b * Sn + qr) * Dn + h * DEP + dc] = f2bf(ctxa[mi][nd][i]);
            }
        }
    }
}

extern "C" void kernel_launch(void* const* d_in, const int* in_sizes, int n_in,
                              void* d_out, int out_size, void* d_ws, size_t ws_size,
                              hipStream_t stream) {
    (void)in_sizes; (void)n_in; (void)out_size; (void)ws_size;
    const float* x  = (const float*)d_in[0];
    const float* wq = (const float*)d_in[1];
    const float* bq = (const float*)d_in[2];
    const float* wk = (const float*)d_in[3];
    const float* bk = (const float*)d_in[4];
    const float* wv = (const float*)d_in[5];
    const float* bv = (const float*)d_in[6];
    const float* wo = (const float*)d_in[7];
    const float* bo = (const float*)d_in[8];

    float* out  = (float*)d_out;
    float* attn = out + (size_t)Bn * Sn * Dn;  // outputs concatenated: (out, attn)

    char* ws = (char*)d_ws;
    unsigned short* xb = (unsigned short*)ws;  ws += (size_t)NTOKn * Dn * 2;       // 8 MB
    unsigned short* wT = (unsigned short*)ws;  ws += (size_t)4 * Dn * Dn * 2;      // 8 MB [q,k,v,o]
    unsigned short* qkv = (unsigned short*)ws; ws += (size_t)3 * NTOKn * Dn * 2;   // 24 MB (v third unused)
    unsigned short* vT = (unsigned short*)ws;  ws += (size_t)NTOKn * Dn * 2;       // 8 MB
    unsigned short* ctx = (unsigned short*)ws;                                     // 8 MB

    const size_t DD = (size_t)Dn * Dn;

    static bool attr_set = false;
    if (!attr_set) {
        hipFuncSetAttribute(reinterpret_cast<const void*>(k_qkv8),
                            hipFuncAttributeMaxDynamicSharedMemorySize, 131072);
        attr_set = true;
    }

    k_prep<<<dim3(5120), 256, 0, stream>>>(x, wq, wk, wv, wo, xb,
                                           wT, wT + DD, wT + 2 * DD, wT + 3 * DD);
    k_qkv8<<<dim3(16, 12), 512, 131072, stream>>>(xb, wT, bq, bk, bv, qkv, vT);
    k_attn<<<dim3(16, 32), 256, 0, stream>>>(qkv, qkv + (size_t)NTOKn * Dn, vT, attn, ctx);
    k_gemm_op<<<dim3(32, 8), 256, 0, stream>>>(ctx, wT + 3 * DD, bo, out, NTOKn, Dn, Dn);
}

// Round 10
// 214.499 us; speedup vs baseline: 1.1316x; 1.0614x over previous
//
#include <hip/hip_runtime.h>
#include <hip/hip_bf16.h>

// Problem constants (reference: B=2, S=2048, D=1024, H=16, DEPTH=64)
constexpr int Bn = 2, Sn = 2048, Dn = 1024, Hn = 16, DEP = 64;
constexpr int NTOKn = Bn * Sn;  // 4096 rows for the token-dim GEMMs

typedef __bf16 bf16x8 __attribute__((ext_vector_type(8)));
typedef float f32x4 __attribute__((ext_vector_type(4)));

__device__ __forceinline__ unsigned short f2bf(float f) {
    union { __hip_bfloat16 h; unsigned short u; } cv;
    cv.h = __float2bfloat16(f);
    return cv.u;
}

// async global->LDS, 16B per lane. LDS dest must be wave-uniform base + lane*16.
__device__ __forceinline__ void gll16(const void* g, void* l) {
    __builtin_amdgcn_global_load_lds(
        (const __attribute__((address_space(1))) unsigned int*)g,
        (__attribute__((address_space(3))) unsigned int*)l, 16, 0, 0);
}

// ---------------- fused prep: x f32->bf16 convert + 4x weight transpose ----------------
__global__ __launch_bounds__(256) void k_prep(const float* __restrict__ x,
                                              const float* __restrict__ w0,
                                              const float* __restrict__ w1,
                                              const float* __restrict__ w2,
                                              const float* __restrict__ w3,
                                              unsigned short* __restrict__ xb,
                                              unsigned short* __restrict__ t0,
                                              unsigned short* __restrict__ t1,
                                              unsigned short* __restrict__ t2,
                                              unsigned short* __restrict__ t3) {
    const int bid = blockIdx.x;
    const int t = threadIdx.x;
    if (bid < 4096) {
        const int idx = (bid * 256 + t) * 4;
        float4 v = *reinterpret_cast<const float4*>(x + idx);
        ushort4 o;
        o.x = f2bf(v.x); o.y = f2bf(v.y); o.z = f2bf(v.z); o.w = f2bf(v.w);
        *reinterpret_cast<ushort4*>(xb + idx) = o;
        return;
    }
    const int b2 = bid - 4096;
    const float* w; unsigned short* tp;
    switch (b2 >> 8) {
        case 0: w = w0; tp = t0; break;
        case 1: w = w1; tp = t1; break;
        case 2: w = w2; tp = t2; break;
        default: w = w3; tp = t3; break;
    }
    __shared__ unsigned short tile[64][65];
    const int k0 = ((b2 & 255) >> 4) * 64, n0 = (b2 & 15) * 64;
    const int c = t & 63, rb = t >> 6;
#pragma unroll
    for (int i = 0; i < 16; ++i) {
        int r = rb + i * 4;
        tile[r][c] = f2bf(w[(size_t)(k0 + r) * Dn + n0 + c]);
    }
    __syncthreads();
#pragma unroll
    for (int i = 0; i < 16; ++i) {
        int n = rb + i * 4;
        tp[(size_t)(n0 + n) * Dn + k0 + c] = tile[c][n];
    }
}

// =================== QKV GEMM, 8-phase-style 256x256 tile ===================
// (counted vmcnt(4), T2 slot-swizzle, T5 setprio)
// Epilogue: Q/K blocks write qkv[z][token][dim]; V blocks (z==2) write the
// TRANSPOSED vT[(b*1024+col)][s] directly as ushort4.
__global__ __launch_bounds__(512, 2) void k_qkv8(const unsigned short* __restrict__ A,
                                                 const unsigned short* __restrict__ Bt,
                                                 const float* __restrict__ bq,
                                                 const float* __restrict__ bk,
                                                 const float* __restrict__ bv,
                                                 unsigned short* __restrict__ qkv,
                                                 unsigned short* __restrict__ vT) {
    extern __shared__ char smem[];  // 131072 bytes
    constexpr int K = 1024, NT = K / 64;  // 16 K-steps

    const int t = threadIdx.x;
    const int w = t >> 6, l = t & 63;
    const int wm = w >> 2, wn = w & 3;
    const int m0 = blockIdx.x * 256;
    const int n0 = blockIdx.y * 256;
    const int z = n0 >> 10;

    const float* bias = (z == 0) ? bq : (z == 1 ? bk : bv);
    float biasv[4];
#pragma unroll
    for (int nf = 0; nf < 4; ++nf)
        biasv[nf] = bias[(n0 + wn * 64 + nf * 16 + (l & 15)) & 1023];

    int aoff[2], boff[2], ldsoff[2];
#pragma unroll
    for (int i = 0; i < 2; ++i) {
        const int idx = i * 512 + t;
        const int row = idx >> 2;
        const int s = ((idx & 3) - row - (row >> 2)) & 3;
        aoff[i] = (m0 + row) * K + s * 8;
        boff[i] = (n0 + row) * K + s * 8;
        ldsoff[i] = idx * 16;
    }

    f32x4 acc[8][4] = {};

#pragma unroll
    for (int kh = 0; kh < 2; ++kh) {
        if (kh == 0) {
#pragma unroll
            for (int i = 0; i < 2; ++i) gll16(A + aoff[i], smem + ldsoff[i]);
#pragma unroll
            for (int i = 0; i < 2; ++i) gll16(Bt + boff[i], smem + 65536 + ldsoff[i]);
        } else {
#pragma unroll
            for (int i = 0; i < 2; ++i) gll16(A + aoff[i] + 32, smem + 16384 + ldsoff[i]);
#pragma unroll
            for (int i = 0; i < 2; ++i) gll16(Bt + boff[i] + 32, smem + 65536 + 16384 + ldsoff[i]);
        }
    }

    for (int kb = 0; kb < NT; ++kb) {
        const int c = kb & 1;
        const int kn = (kb + 1 < NT) ? kb + 1 : NT - 1;
        const int cn = c ^ 1;
        const int Abase = c * 32768;
        const int Bbase = 65536 + c * 32768;
        const int AbaseN = cn * 32768;
        const int BbaseN = 65536 + cn * 32768;

        bf16x8 bf[4], af[4];

#pragma unroll
        for (int ph = 0; ph < 4; ++ph) {
            const int kk = ph >> 1;
            const int mb = (ph & 1) * 4;

            if ((ph & 1) == 0) {
                asm volatile("s_waitcnt vmcnt(4)" ::: "memory");
            }
            __builtin_amdgcn_s_barrier();
            __builtin_amdgcn_sched_barrier(0);

            if ((ph & 1) == 0) {
#pragma unroll
                for (int nf = 0; nf < 4; ++nf) {
                    const int row = wn * 64 + nf * 16 + (l & 15);
                    const int byte = Bbase + kk * 16384 + row * 64 +
                                     ((((l >> 4) + row + (row >> 2)) & 3) * 16);
                    bf[nf] = *reinterpret_cast<const bf16x8*>(smem + byte);
                }
            }
#pragma unroll
            for (int mfl = 0; mfl < 4; ++mfl) {
                const int row = wm * 128 + (mb + mfl) * 16 + (l & 15);
                const int byte = Abase + kk * 16384 + row * 64 +
                                 ((((l >> 4) + row + (row >> 2)) & 3) * 16);
                af[mfl] = *reinterpret_cast<const bf16x8*>(smem + byte);
            }

            {
                const int khs = ph >> 1;
                if ((ph & 1) == 0) {
#pragma unroll
                    for (int i = 0; i < 2; ++i)
                        gll16(A + aoff[i] + kn * 64 + khs * 32,
                              smem + AbaseN + khs * 16384 + ldsoff[i]);
                } else {
#pragma unroll
                    for (int i = 0; i < 2; ++i)
                        gll16(Bt + boff[i] + kn * 64 + khs * 32,
                              smem + BbaseN + khs * 16384 + ldsoff[i]);
                }
            }

            asm volatile("s_waitcnt lgkmcnt(0)" ::: "memory");
            __builtin_amdgcn_sched_barrier(0);
            __builtin_amdgcn_s_setprio(1);
#pragma unroll
            for (int mfl = 0; mfl < 4; ++mfl)
#pragma unroll
                for (int nf = 0; nf < 4; ++nf)
                    acc[mb + mfl][nf] = __builtin_amdgcn_mfma_f32_16x16x32_bf16(
                        af[mfl], bf[nf], acc[mb + mfl][nf], 0, 0, 0);
            __builtin_amdgcn_s_setprio(0);
        }
    }

    asm volatile("s_waitcnt vmcnt(0)" ::: "memory");

    if (z < 2) {
        unsigned short* outz = qkv + (size_t)z * NTOKn * Dn;
#pragma unroll
        for (int mf = 0; mf < 8; ++mf) {
            const int row = m0 + wm * 128 + mf * 16 + (l >> 4) * 4;
#pragma unroll
            for (int nf = 0; nf < 4; ++nf) {
                const int col = (n0 + wn * 64 + nf * 16 + (l & 15)) & 1023;
#pragma unroll
                for (int i = 0; i < 4; ++i)
                    outz[(size_t)(row + i) * Dn + col] = f2bf(acc[mf][nf][i] + biasv[nf]);
            }
        }
    } else {
        // V: write transposed vT[(b*1024 + col)][s], 4 consecutive s per lane
#pragma unroll
        for (int mf = 0; mf < 8; ++mf) {
            const int row = m0 + wm * 128 + mf * 16 + (l >> 4) * 4;
            const int b = row >> 11, s = row & 2047;
#pragma unroll
            for (int nf = 0; nf < 4; ++nf) {
                const int col = (n0 + wn * 64 + nf * 16 + (l & 15)) & 1023;
                ushort4 o;
                o.x = f2bf(acc[mf][nf][0] + biasv[nf]);
                o.y = f2bf(acc[mf][nf][1] + biasv[nf]);
                o.z = f2bf(acc[mf][nf][2] + biasv[nf]);
                o.w = f2bf(acc[mf][nf][3] + biasv[nf]);
                *reinterpret_cast<ushort4*>(vT + ((size_t)(b * 1024 + col)) * Sn + s) = o;
            }
        }
    }
}

// ---------------- bf16 GEMM (m97 structure, 128x128) for the out-projection ----------------
__global__ __launch_bounds__(256) void k_gemm_op(const unsigned short* __restrict__ A,
                                                 const unsigned short* __restrict__ Bt,
                                                 const float* __restrict__ bias,
                                                 float* __restrict__ C,
                                                 int M, int N, int K) {
    __shared__ unsigned short As[128][32];
    __shared__ unsigned short Bs[128][32];
    const int t = threadIdx.x;
    const int w = t >> 6, l = t & 63;
    const int m0 = blockIdx.x * 128, n0 = blockIdx.y * 128;
    const int wr = (w >> 1) * 64, wc = (w & 1) * 64;

    const int lrow = t >> 2;
    const int lcol = (t & 3) * 8;
    const unsigned short* gA = A + (size_t)(m0 + lrow) * K + lcol;
    const unsigned short* gB = Bt + (size_t)(n0 + lrow) * K + lcol;
    unsigned short* lA = &As[0][0] + t * 8;
    unsigned short* lB = &Bs[0][0] + t * 8;

    f32x4 acc[4][4] = {};

    for (int k0 = 0; k0 < K; k0 += 32) {
        __syncthreads();
        gll16(gA + k0, lA);
        gll16(gA + (size_t)64 * K + k0, lA + 2048);
        gll16(gB + k0, lB);
        gll16(gB + (size_t)64 * K + k0, lB + 2048);
        __syncthreads();

        bf16x8 af[4], bfv[4];
#pragma unroll
        for (int i = 0; i < 4; ++i)
            af[i] = *reinterpret_cast<const bf16x8*>(&As[wr + i * 16 + (l & 15)][(l >> 4) * 8]);
#pragma unroll
        for (int i = 0; i < 4; ++i)
            bfv[i] = *reinterpret_cast<const bf16x8*>(&Bs[wc + i * 16 + (l & 15)][(l >> 4) * 8]);
#pragma unroll
        for (int mi = 0; mi < 4; ++mi)
#pragma unroll
            for (int ni = 0; ni < 4; ++ni)
                acc[mi][ni] =
                    __builtin_amdgcn_mfma_f32_16x16x32_bf16(af[mi], bfv[ni], acc[mi][ni], 0, 0, 0);
    }

#pragma unroll
    for (int mi = 0; mi < 4; ++mi) {
        const int row = m0 + wr + mi * 16 + (l >> 4) * 4;
#pragma unroll
        for (int ni = 0; ni < 4; ++ni) {
            const int col = n0 + wc + ni * 16 + (l & 15);
            const float bv = bias[col];
#pragma unroll
            for (int i = 0; i < 4; ++i)
                C[(size_t)(row + i) * N + col] = acc[mi][ni][i] + bv;
        }
    }
}

// ---------------- fused attention: attn = relu(QK^T*scale), ctx = attn @ V ----------------
// R7 structure (best known) with ONE change: attn stores are sourced from the
// bf16 Ps LDS tile (already written for PV) with a full-line mapping — per
// instruction 8 rows x 8 lanes x 16B = aligned 128B lines (no partial-line
// writes). bf16->f32 via u<<16 (1 VALU/elem). sa no longer persists across
// iterations (register relief vs R7). Counted vmcnt(16): 8 loads + 16 stores
// per iter, <=16 outstanding => loads retired, stores never drained (T4).
__global__ __launch_bounds__(256, 2) void k_attn(const unsigned short* __restrict__ Qb,
                                                 const unsigned short* __restrict__ Kb,
                                                 const unsigned short* __restrict__ VTb,
                                                 float* __restrict__ attn,
                                                 unsigned short* __restrict__ ctx) {
    __shared__ unsigned short Ks[128 * 64];
    __shared__ unsigned short Vs[64 * 128];
    __shared__ unsigned short Ps[4][32][136];

    const int t = threadIdx.x;
    const int w = t >> 6, l = t & 63;

    // XCD-aware bijective remap (dispatch round-robins linear%8 across XCDs)
    const int lin = blockIdx.x + 16 * blockIdx.y;
    const int xcd = lin & 7, idx = lin >> 3;
    const int bh = xcd * 4 + (idx >> 4);
    const int q0 = (idx & 15) * 128;
    const int b = bh >> 4, h = bh & 15;
    const float scale = 0.125f;  // 1/sqrt(64)

    bf16x8 qf[2][2];
#pragma unroll
    for (int mi = 0; mi < 2; ++mi)
#pragma unroll
        for (int kk = 0; kk < 2; ++kk)
            qf[mi][kk] = *reinterpret_cast<const bf16x8*>(
                Qb + (size_t)(b * Sn + q0 + w * 32 + mi * 16 + (l & 15)) * Dn + h * DEP +
                kk * 32 + (l >> 4) * 8);

    const int krow = t >> 3;
    const int kcolswz = ((t & 7) * 8) ^ ((krow & 7) << 3);
    const int vrow = t >> 4;
    const int vcolswz = ((t & 15) * 8) ^ ((vrow & 7) << 3);
    unsigned short* lK = Ks + t * 8;
    unsigned short* lV = Vs + t * 8;

    f32x4 ctxa[2][4] = {};
    float* const abase = attn + (size_t)bh * Sn * Sn + (size_t)(q0 + w * 32) * Sn;

    auto STAGE = [&](int kb) {
#pragma unroll
        for (int is = 0; is < 4; ++is) {
            gll16(Kb + (size_t)(b * Sn + kb * 128 + is * 32 + krow) * Dn + h * DEP + kcolswz,
                  lK + is * 2048);
            gll16(VTb + (size_t)(bh * DEP + is * 16 + vrow) * Sn + kb * 128 + vcolswz,
                  lV + is * 2048);
        }
    };

    // QK^T -> relu/scale -> P (bf16) into per-wave Ps (R7 layout)
    auto QKT = [&]() {
        f32x4 sa[2][8];
#pragma unroll
        for (int mi = 0; mi < 2; ++mi)
#pragma unroll
            for (int nj = 0; nj < 8; ++nj)
                sa[mi][nj] = (f32x4){0.f, 0.f, 0.f, 0.f};
#pragma unroll
        for (int nj = 0; nj < 8; ++nj) {
            const int kr = nj * 16 + (l & 15);
#pragma unroll
            for (int kk = 0; kk < 2; ++kk) {
                const int kidx = (kr * 64 + kk * 32 + (l >> 4) * 8) ^ ((kr & 7) << 3);
                const bf16x8 bfr = *reinterpret_cast<const bf16x8*>(Ks + kidx);
                sa[0][nj] = __builtin_amdgcn_mfma_f32_16x16x32_bf16(qf[0][kk], bfr, sa[0][nj], 0, 0, 0);
                sa[1][nj] = __builtin_amdgcn_mfma_f32_16x16x32_bf16(qf[1][kk], bfr, sa[1][nj], 0, 0, 0);
            }
        }
#pragma unroll
        for (int mi = 0; mi < 2; ++mi) {
#pragma unroll
            for (int nj = 0; nj < 8; ++nj) {
                const int kc = nj * 16 + (l & 15);
#pragma unroll
                for (int i = 0; i < 4; ++i) {
                    float p = sa[mi][nj][i] * scale;
                    p = p > 0.f ? p : 0.f;
                    Ps[w][mi * 16 + (l >> 4) * 4 + i][kc] = f2bf(p);
                }
            }
        }
    };

    auto PV = [&]() {
        bf16x8 pf[2][4];
#pragma unroll
        for (int mi = 0; mi < 2; ++mi)
#pragma unroll
            for (int kk = 0; kk < 4; ++kk)
                pf[mi][kk] = *reinterpret_cast<const bf16x8*>(
                    &Ps[w][mi * 16 + (l & 15)][kk * 32 + (l >> 4) * 8]);
#pragma unroll
        for (int nd = 0; nd < 4; ++nd) {
            const int vr = nd * 16 + (l & 15);
#pragma unroll
            for (int kk = 0; kk < 4; ++kk) {
                const int vidx = (vr * 128 + kk * 32 + (l >> 4) * 8) ^ ((vr & 7) << 3);
                const bf16x8 vfr = *reinterpret_cast<const bf16x8*>(Vs + vidx);
                ctxa[0][nd] = __builtin_amdgcn_mfma_f32_16x16x32_bf16(pf[0][kk], vfr, ctxa[0][nd], 0, 0, 0);
                ctxa[1][nd] = __builtin_amdgcn_mfma_f32_16x16x32_bf16(pf[1][kk], vfr, ctxa[1][nd], 0, 0, 0);
            }
        }
    };

    // Full-line attn stores from Ps: per j, 8 rows x (8 lanes x 16B) = aligned
    // 128B lines. Reads are same-wave (Ps written by own QKT) -> no barrier.
    auto STORE_PS = [&](int kb) {
        float* arow = abase + kb * 128;
#pragma unroll
        for (int j = 0; j < 16; ++j) {
            const int row = (j & 3) * 8 + (l >> 3);
            const int col = (l & 7) * 4 + (j >> 2) * 32;
            ushort4 p = *reinterpret_cast<const ushort4*>(&Ps[w][row][col]);
            f32x4 v;
            v[0] = __uint_as_float((unsigned)p.x << 16);
            v[1] = __uint_as_float((unsigned)p.y << 16);
            v[2] = __uint_as_float((unsigned)p.z << 16);
            v[3] = __uint_as_float((unsigned)p.w << 16);
            *reinterpret_cast<f32x4*>(arow + (size_t)row * Sn + col) = v;
        }
    };

    STAGE(0);
    asm volatile("s_waitcnt vmcnt(0)" ::: "memory");
    __builtin_amdgcn_s_barrier();
    __builtin_amdgcn_sched_barrier(0);
    QKT();
    PV();

    for (int kb = 1; kb < Sn / 128; ++kb) {
        asm volatile("s_waitcnt lgkmcnt(0)" ::: "memory");
        __builtin_amdgcn_s_barrier();
        __builtin_amdgcn_sched_barrier(0);
        STAGE(kb);                             // 8 loads (oldest)
        asm volatile("" ::: "memory");         // keep stores after loads in issue order
        STORE_PS(kb - 1);                      // 16 full-line stores from Ps
        asm volatile("s_waitcnt vmcnt(16)" ::: "memory");  // loads retired, stores free
        __builtin_amdgcn_s_barrier();
        __builtin_amdgcn_sched_barrier(0);
        QKT();
        PV();
    }
    STORE_PS(Sn / 128 - 1);

#pragma unroll
    for (int mi = 0; mi < 2; ++mi) {
#pragma unroll
        for (int nd = 0; nd < 4; ++nd) {
            const int dc = nd * 16 + (l & 15);
#pragma unroll
            for (int i = 0; i < 4; ++i) {
                const int qr = q0 + w * 32 + mi * 16 + (l >> 4) * 4 + i;
                ctx[(size_t)(b * Sn + qr) * Dn + h * DEP + dc] = f2bf(ctxa[mi][nd][i]);
            }
        }
    }
}

extern "C" void kernel_launch(void* const* d_in, const int* in_sizes, int n_in,
                              void* d_out, int out_size, void* d_ws, size_t ws_size,
                              hipStream_t stream) {
    (void)in_sizes; (void)n_in; (void)out_size; (void)ws_size;
    const float* x  = (const float*)d_in[0];
    const float* wq = (const float*)d_in[1];
    const float* bq = (const float*)d_in[2];
    const float* wk = (const float*)d_in[3];
    const float* bk = (const float*)d_in[4];
    const float* wv = (const float*)d_in[5];
    const float* bv = (const float*)d_in[6];
    const float* wo = (const float*)d_in[7];
    const float* bo = (const float*)d_in[8];

    float* out  = (float*)d_out;
    float* attn = out + (size_t)Bn * Sn * Dn;  // outputs concatenated: (out, attn)

    char* ws = (char*)d_ws;
    unsigned short* xb = (unsigned short*)ws;  ws += (size_t)NTOKn * Dn * 2;       // 8 MB
    unsigned short* wT = (unsigned short*)ws;  ws += (size_t)4 * Dn * Dn * 2;      // 8 MB [q,k,v,o]
    unsigned short* qkv = (unsigned short*)ws; ws += (size_t)3 * NTOKn * Dn * 2;   // 24 MB (v third unused)
    unsigned short* vT = (unsigned short*)ws;  ws += (size_t)NTOKn * Dn * 2;       // 8 MB
    unsigned short* ctx = (unsigned short*)ws;                                     // 8 MB

    const size_t DD = (size_t)Dn * Dn;

    static bool attr_set = false;
    if (!attr_set) {
        hipFuncSetAttribute(reinterpret_cast<const void*>(k_qkv8),
                            hipFuncAttributeMaxDynamicSharedMemorySize, 131072);
        attr_set = true;
    }

    k_prep<<<dim3(5120), 256, 0, stream>>>(x, wq, wk, wv, wo, xb,
                                           wT, wT + DD, wT + 2 * DD, wT + 3 * DD);
    k_qkv8<<<dim3(16, 12), 512, 131072, stream>>>(xb, wT, bq, bk, bv, qkv, vT);
    k_attn<<<dim3(16, 32), 256, 0, stream>>>(qkv, qkv + (size_t)NTOKn * Dn, vT, attn, ctx);
    k_gemm_op<<<dim3(32, 8), 256, 0, stream>>>(ctx, wT + 3 * DD, bo, out, NTOKn, Dn, Dn);
}